// Round 22
// baseline (204.160 us; speedup 1.0000x reference)
//
#include <hip/hip_runtime.h>
#include <stdint.h>

// KohonenMap: x [65536,64] f32, nodes [4096,64] f32
// out = concat( node_repr [65536,64] f32 , winning_indices [65536] as f32 )
//
// argmin_k ||x-n_k|| = argmin_k M'_k,  M'_k = 0.5*n2_k - x.n_k  (signed,
// |M'| < 64 -> 5-bit pack error <= 2.4e-4)
// Phase 1 (r22 = r9 barrier-free L2-direct + 16 waves/CU): NO LDS, NO
//   barriers. B-fragments streamed L2->registers (rotating 8-VGPR c-chunks,
//   compiler-counted vmcnt). 64 rows/wave (2 row-tiles = 2 MFMA chains, the
//   ILP r10 proved necessary), grid 1024 = 256 row-blocks x 4 node-quarters
//   (r9 was 8 waves/CU and issue-starved; 4 blocks/CU doubles TLP).
//   Packed-b1 argmin (5-bit local tile id), v2 unpacked, exact index
//   recovered post-loop. Candidate per (row,quarter): (b1,v2) at
//   out[row*64+q*2], exact idx at out[row*64+8+q].
// Merge: combine 4 quarters (exact-idx tie-break), write index, gather repr,
//   flag margin<=0.0065.
// Phase 2: 2-row-batched exact f64 re-solve (r18-proven).
//
// ws layout (1.36 MB, unchanged since r2):
//   [0]        int    refine_cnt
//   [64]       int    refine_list[65536]       (256 KiB)
//   [262208]   float  hn2f[4096] = 0.5*n2      (16 KiB)
//   [278592]   double n2d[4096]                (32 KiB)
//   [311360]   u16    bfrag[128][4][2][512]    (1 MiB) fragment-order bf16 of (-nodes), hi/lo

typedef unsigned short u16;
typedef __bf16 bf16x8 __attribute__((ext_vector_type(8)));
typedef unsigned short u16x8 __attribute__((ext_vector_type(8)));
typedef float f32x16 __attribute__((ext_vector_type(16)));

#define B_ROWS 65536
#define K_NODES 4096
#define DIM 64
#define MERGE_TAU 0.0065f

#define OFF_LIST 64
#define OFF_N2F  262208
#define OFF_N2D  278592
#define OFF_BFRAG 311360

__device__ __forceinline__ u16 bf16_rne(float f, float& back) {
    uint32_t u = __float_as_uint(f);
    uint32_t r = u + 0x7FFFu + ((u >> 16) & 1u);
    u16 h = (u16)(r >> 16);
    back = __uint_as_float(((uint32_t)h) << 16);
    return h;
}

__device__ __forceinline__ float pack_tile5(float v, uint32_t t) {
    return __uint_as_float((__float_as_uint(v) & 0xFFFFFFE0u) | t);   // 5-bit id
}

// ---------------- prep (merged): bfrag(-nodes) + hn2 + n2d + ref_cnt ---------
__global__ __launch_bounds__(256) void prep(const float* __restrict__ nodes,
                                            u16* __restrict__ bfrag,
                                            float* __restrict__ hn2f,
                                            double* __restrict__ n2d,
                                            int* __restrict__ ref_cnt) {
    if (blockIdx.x < 128) {
        int idx = blockIdx.x * 256 + threadIdx.x;   // (t 0..127, l 0..63, c 0..3)
        int t = idx >> 8;
        int rem = idx & 255;
        int l = rem >> 2, c = rem & 3;
        const float* row = nodes + (size_t)(t * 32 + (l & 31)) * DIM + ((l >> 5) * 8);
        float4 f0 = *(const float4*)(row + c * 16);
        float4 f1 = *(const float4*)(row + c * 16 + 4);
        float fs[8] = {-f0.x, -f0.y, -f0.z, -f0.w, -f1.x, -f1.y, -f1.z, -f1.w};
        u16x8 hv, lv;
        #pragma unroll
        for (int j = 0; j < 8; ++j) {
            float hf, dummy;
            u16 hb = bf16_rne(fs[j], hf);
            u16 lb = bf16_rne(fs[j] - hf, dummy);
            hv[j] = hb; lv[j] = lb;
        }
        int base = ((t * 4 + c) * 2) * 512 + l * 8;  // u16 index
        *(u16x8*)(bfrag + base)       = hv;
        *(u16x8*)(bfrag + base + 512) = lv;
    } else {
        if (blockIdx.x == 128 && threadIdx.x == 0) *ref_cnt = 0;
        int k = (blockIdx.x - 128) * 256 + threadIdx.x;
        if (k < K_NODES) {
            const float* r = nodes + (size_t)k * DIM;
            double s = 0.0;
            #pragma unroll
            for (int d = 0; d < DIM; ++d) { double v = (double)r[d]; s += v * v; }
            n2d[k] = s;
            hn2f[k] = 0.5f * (float)s;
        }
    }
}

// ---- phase 1: barrier-free, LDS-free, quarter streamed L2->regs -------------
__global__ __launch_bounds__(256, 2) void phase1(const float* __restrict__ x,
                                                 const u16* __restrict__ bfrag_g,
                                                 const float* __restrict__ hn2f,
                                                 float* __restrict__ out) {
    const int tid  = threadIdx.x;
    const int lane = tid & 63;
    const int w    = tid >> 6;              // wave 0..3
    const int col  = lane & 31;
    const int lh   = lane >> 5;
    const int rb   = blockIdx.x >> 2;       // row block 0..255
    const int qid  = blockIdx.x & 3;        // node quarter
    const int rbase = rb * 256 + w * 64;    // wave owns rows [rbase, rbase+64)

    // A fragments for 2 row-tiles, split hi/lo. d = lh*8 + c*16 + j
    bf16x8 ah[2][4], al[2][4];
    #pragma unroll
    for (int t = 0; t < 2; ++t) {
        const float* xp = x + (size_t)(rbase + t * 32 + col) * DIM + lh * 8;
        #pragma unroll
        for (int c = 0; c < 4; ++c) {
            float4 f0 = *(const float4*)(xp + c * 16);
            float4 f1 = *(const float4*)(xp + c * 16 + 4);
            float fs[8] = {f0.x, f0.y, f0.z, f0.w, f1.x, f1.y, f1.z, f1.w};
            u16x8 hv, lv;
            #pragma unroll
            for (int j = 0; j < 8; ++j) {
                float hf, dummy;
                u16 hb = bf16_rne(fs[j], hf);
                u16 lb = bf16_rne(fs[j] - hf, dummy);
                hv[j] = hb; lv[j] = lb;
            }
            union { u16x8 u; bf16x8 b; } cvh, cvl;
            cvh.u = hv; cvl.u = lv;
            ah[t][c] = cvh.b; al[t][c] = cvl.b;
        }
    }

    float b1[2][16], v2[2][16];
    #pragma unroll
    for (int t = 0; t < 2; ++t)
        #pragma unroll
        for (int q = 0; q < 16; ++q) { b1[t][q] = 3.4e38f; v2[t][q] = 3.4e38f; }

    // B stream base for this quarter: 32 tiles x 8192 B, per-lane 16B slots.
    const char* qbase = (const char*)bfrag_g + (size_t)qid * 262144 + (size_t)lane * 16;
    const float* hp = hn2f + qid * 1024 + col;

    bf16x8 h0, l0, h1, l1, h2, l2, h3, l3;

    #define LD(dsth, dstl, tt, cc) do {                                         \
        const char* _p = qbase + (size_t)(tt) * 8192 + (cc) * 2048;             \
        dsth = *(const bf16x8*)(_p);                                            \
        dstl = *(const bf16x8*)(_p + 1024);                                     \
    } while (0)

    #define MF6(B_h, B_l, cc) do {                                              \
        a0 = __builtin_amdgcn_mfma_f32_32x32x16_bf16(ah[0][cc], B_h, a0, 0, 0, 0); \
        a1 = __builtin_amdgcn_mfma_f32_32x32x16_bf16(ah[1][cc], B_h, a1, 0, 0, 0); \
        a0 = __builtin_amdgcn_mfma_f32_32x32x16_bf16(al[0][cc], B_h, a0, 0, 0, 0); \
        a1 = __builtin_amdgcn_mfma_f32_32x32x16_bf16(al[1][cc], B_h, a1, 0, 0, 0); \
        a0 = __builtin_amdgcn_mfma_f32_32x32x16_bf16(ah[0][cc], B_l, a0, 0, 0, 0); \
        a1 = __builtin_amdgcn_mfma_f32_32x32x16_bf16(ah[1][cc], B_l, a1, 0, 0, 0); \
    } while (0)

    LD(h0, l0, 0, 0);                       // prologue: tile0 c0
    LD(h1, l1, 0, 1);                       // tile0 c1
    float hn2_cur = hp[0];

    for (int t = 0; t < 32; ++t) {
        const int tn = (t + 1 < 32) ? t + 1 : 31;
        float hn2_nxt = hp[tn * 32];
        f32x16 a0, a1;
        #pragma unroll
        for (int q = 0; q < 16; ++q) { a0[q] = hn2_cur; a1[q] = hn2_cur; }

        LD(h2, l2, t, 2);
        MF6(h0, l0, 0);
        LD(h3, l3, t, 3);
        MF6(h1, l1, 1);
        LD(h0, l0, tn, 0);
        MF6(h2, l2, 2);
        LD(h1, l1, tn, 1);
        MF6(h3, l3, 3);

        const uint32_t tb = (uint32_t)t;
        #pragma unroll
        for (int q = 0; q < 16; ++q) {
            float p0 = pack_tile5(a0[q], tb);
            v2[0][q] = fminf(v2[0][q], fmaxf(p0, b1[0][q]));
            b1[0][q] = fminf(b1[0][q], p0);
            float p1 = pack_tile5(a1[q], tb);
            v2[1][q] = fminf(v2[1][q], fmaxf(p1, b1[1][q]));
            b1[1][q] = fminf(b1[1][q], p1);
        }
        hn2_cur = hn2_nxt;
    }
    #undef LD
    #undef MF6

    // recover GLOBAL node index from b1's 5-bit tile id + col (+ quarter offset)
    int gi[2][16];
    #pragma unroll
    for (int t = 0; t < 2; ++t)
        #pragma unroll
        for (int q = 0; q < 16; ++q)
            gi[t][q] = qid * 1024 + (int)(__float_as_uint(b1[t][q]) & 31u) * 32 + col;

    // reduce (b1, gi, v2) across the 32 cols (within each lane-half)
    #pragma unroll
    for (int off = 1; off < 32; off <<= 1) {
        #pragma unroll
        for (int t = 0; t < 2; ++t)
            #pragma unroll
            for (int q = 0; q < 16; ++q) {
                float ov  = __shfl_xor(b1[t][q], off, 64);
                float ov2 = __shfl_xor(v2[t][q], off, 64);
                int   og  = __shfl_xor(gi[t][q], off, 64);
                float hi2 = fmaxf(b1[t][q], ov);
                v2[t][q] = fminf(fminf(v2[t][q], ov2), hi2);
                bool take = (ov < b1[t][q]) || (ov == b1[t][q] && og < gi[t][q]);
                b1[t][q] = take ? ov : b1[t][q];
                gi[t][q] = take ? og : gi[t][q];
            }
    }

    if (col == 0) {                  // lanes 0 and 32 of each wave
        #pragma unroll
        for (int t = 0; t < 2; ++t)
            #pragma unroll
            for (int q = 0; q < 16; ++q) {
                int rloc = (q & 3) + 8 * (q >> 2) + 4 * lh;   // C/D layout (verified r1-r21)
                int grow = rb * 256 + w * 64 + t * 32 + rloc;
                // candidate in out's repr row (overwritten by merge's gather):
                // (b1, v2) at q*2, exact global index as float at 8+q
                *(float2*)(out + (size_t)grow * DIM + qid * 2) = make_float2(b1[t][q], v2[t][q]);
                out[(size_t)grow * DIM + 8 + qid] = (float)gi[t][q];
            }
    }
}

// -------- merge: combine quarters, write index, gather, flag refines ---------
__global__ __launch_bounds__(256) void merge_k(const float* __restrict__ nodes,
                                               float* __restrict__ out,
                                               int* __restrict__ ref_cnt,
                                               int* __restrict__ ref_list) {
    __shared__ int s_win[256];
    const int tid = threadIdx.x;
    const int row = blockIdx.x * 256 + tid;
    float4 cA = *(const float4*)(out + (size_t)row * DIM);       // q0:(b,v) q1:(b,v)
    float4 cB = *(const float4*)(out + (size_t)row * DIM + 4);   // q2:(b,v) q3:(b,v)
    float4 ci = *(const float4*)(out + (size_t)row * DIM + 8);   // exact idx q0..q3
    float bv[4] = {cA.x, cA.z, cB.x, cB.z};
    float vv[4] = {cA.y, cA.w, cB.y, cB.w};
    int   iv[4] = {(int)ci.x, (int)ci.y, (int)ci.z, (int)ci.w};
    float wb = bv[0]; int wi = iv[0]; float sec = 3.4e38f;
    #pragma unroll
    for (int q = 1; q < 4; ++q) {
        bool take = (bv[q] < wb) || (bv[q] == wb && iv[q] < wi);
        sec = fminf(sec, take ? wb : bv[q]);
        wb = take ? bv[q] : wb;
        wi = take ? iv[q] : wi;
    }
    sec = fminf(fminf(sec, fminf(vv[0], vv[1])), fminf(vv[2], vv[3]));
    out[(size_t)B_ROWS * DIM + row] = (float)wi;
    if (sec - wb <= MERGE_TAU) {
        int slot = atomicAdd(ref_cnt, 1);
        ref_list[slot] = row;
    }
    s_win[tid] = wi;
    __syncthreads();                 // all candidate reads done before gather overwrites
    const int base_row = blockIdx.x * 256;
    for (int i = tid; i < 256 * 16; i += 256) {
        int rr = i >> 4, cc = i & 15;
        int wn = s_win[rr];
        float4 v = *(const float4*)(nodes + (size_t)wn * DIM + cc * 4);
        *(float4*)(out + (size_t)(base_row + rr) * DIM + cc * 4) = v;
    }
}

// ------ phase 2: exact f64 re-solve, 2 rows per nodes pass -------------------
__global__ __launch_bounds__(256) void phase2(const float* __restrict__ x,
                                              const float* __restrict__ nodes,
                                              const double* __restrict__ n2d,
                                              const int* __restrict__ ref_cnt,
                                              const int* __restrict__ ref_list,
                                              float* __restrict__ out) {
    __shared__ double xsA[DIM], xsB[DIM];
    __shared__ double sval[256];
    __shared__ int    sidx[256];
    __shared__ int    rows_s[2];
    const int tid = threadIdx.x;
    const int cnt = *ref_cnt;
    for (int b0 = blockIdx.x * 2; b0 < cnt; b0 += gridDim.x * 2) {
        const int nr = min(2, cnt - b0);
        __syncthreads();                 // guard xs/rows reuse across batches
        if (tid < 2) rows_s[tid] = ref_list[b0 + min(tid, nr - 1)];
        __syncthreads();
        if (tid < DIM) {
            xsA[tid] = (double)x[(size_t)rows_s[0] * DIM + tid];
            xsB[tid] = (double)x[(size_t)rows_s[1] * DIM + tid];
        }
        __syncthreads();

        double bestA = 1e300, bestB = 1e300;
        int    biA = K_NODES, biB = K_NODES;
        for (int k = tid; k < K_NODES; k += 256) {
            const float4* np4 = (const float4*)(nodes + (size_t)k * DIM);
            double a0 = 0.0, a1 = 0.0, b0d = 0.0, b1d = 0.0;
            #pragma unroll
            for (int t = 0; t < 16; t += 2) {
                float4 w0 = np4[t], w1 = np4[t + 1];
                a0 += xsA[t*4+0]*(double)w0.x + xsA[t*4+1]*(double)w0.y
                    + xsA[t*4+2]*(double)w0.z + xsA[t*4+3]*(double)w0.w;
                b0d += xsB[t*4+0]*(double)w0.x + xsB[t*4+1]*(double)w0.y
                     + xsB[t*4+2]*(double)w0.z + xsB[t*4+3]*(double)w0.w;
                a1 += xsA[t*4+4]*(double)w1.x + xsA[t*4+5]*(double)w1.y
                    + xsA[t*4+6]*(double)w1.z + xsA[t*4+7]*(double)w1.w;
                b1d += xsB[t*4+4]*(double)w1.x + xsB[t*4+5]*(double)w1.y
                     + xsB[t*4+6]*(double)w1.z + xsB[t*4+7]*(double)w1.w;
            }
            const double nn = n2d[k];
            double sA = nn - 2.0 * (a0 + a1);
            double sB = nn - 2.0 * (b0d + b1d);
            if (sA < bestA) { bestA = sA; biA = k; }
            if (sB < bestB) { bestB = sB; biB = k; }
        }

        #pragma unroll 1
        for (int r = 0; r < nr; ++r) {
            sval[tid] = (r == 0) ? bestA : bestB;
            sidx[tid] = (r == 0) ? biA : biB;
            __syncthreads();
            for (int stride = 128; stride > 0; stride >>= 1) {
                if (tid < (unsigned)stride) {
                    double ov = sval[tid + stride];
                    int    oi = sidx[tid + stride];
                    if (ov < sval[tid] || (ov == sval[tid] && oi < sidx[tid])) {
                        sval[tid] = ov; sidx[tid] = oi;
                    }
                }
                __syncthreads();
            }
            const int wn = sidx[0];
            const int row = rows_s[r];
            if (tid == 0) out[(size_t)B_ROWS * DIM + row] = (float)wn;
            if (tid < 16) {
                float4 v = *(const float4*)(nodes + (size_t)wn * DIM + tid * 4);
                *(float4*)(out + (size_t)row * DIM + tid * 4) = v;
            }
            __syncthreads();
        }
    }
}

extern "C" void kernel_launch(void* const* d_in, const int* in_sizes, int n_in,
                              void* d_out, int out_size, void* d_ws, size_t ws_size,
                              hipStream_t stream) {
    const float* x     = (const float*)d_in[0];
    const float* nodes = (const float*)d_in[1];
    float* out = (float*)d_out;
    char*  ws  = (char*)d_ws;

    int*    ref_cnt  = (int*)ws;
    int*    ref_list = (int*)(ws + OFF_LIST);
    float*  hn2f     = (float*)(ws + OFF_N2F);
    double* n2d      = (double*)(ws + OFF_N2D);
    u16*    bfrag    = (u16*)(ws + OFF_BFRAG);

    prep<<<144, 256, 0, stream>>>(nodes, bfrag, hn2f, n2d, ref_cnt);
    phase1<<<1024, 256, 0, stream>>>(x, bfrag, hn2f, out);
    merge_k<<<B_ROWS / 256, 256, 0, stream>>>(nodes, out, ref_cnt, ref_list);
    phase2<<<1024, 256, 0, stream>>>(x, nodes, n2d, ref_cnt, ref_list, out);
}

// Round 23
// 169.138 us; speedup vs baseline: 1.2071x; 1.2071x over previous
//
#include <hip/hip_runtime.h>
#include <stdint.h>

// KohonenMap: x [65536,64] f32, nodes [4096,64] f32
// out = concat( node_repr [65536,64] f32 , winning_indices [65536] as f32 )
//
// argmin_k ||x-n_k|| = argmin_k M'_k,  M'_k = 0.5*n2_k - x.n_k = (dist^2 - x2)/2
// (signed; |M'| < 64 guaranteed -> 6-bit pack error <= 2^-17*64 = 4.8e-4)
// Phase 1 (= r18's proven 120us structure + med3 argmin): split-bf16 MFMA
//   (3 products hh+lh+hl, nodes pre-negated), 64 rows/wave, node-half split
//   (grid 512), 4 waves/block, 2 blocks/CU, LDS double-buffered 32 KiB stages
//   via global_load_lds. Packed-b1 argmin (6-bit stage-local tile id); v2
//   update via v_med3_f32 (min(v2,max(p,b1)) == med3(v2,p,b1) given b1<=v2)
//   -> 3 VALU/score. Exact index recovered post-loop. Candidate per
//   (row,half): (b1,v2) at out[row*64+h*2], index at out[row*64+4+h].
// Merge: combine halves, write index, gather repr, flag margin<=0.0065
//   (= r13/r16-validated 0.006 physical + 4.8e-4 pack bound).
// Phase 2: 2-row-batched exact f64 re-solve (r18-proven).
//
// ws layout (1.36 MB, unchanged since r2):
//   [0]        int    refine_cnt
//   [64]       int    refine_list[65536]       (256 KiB)
//   [262208]   float  hn2f[4096] = 0.5*n2      (16 KiB)
//   [278592]   double n2d[4096]                (32 KiB)
//   [311360]   u16    bfrag[128][4][2][512]    (1 MiB) fragment-order bf16 of (-nodes), hi/lo

typedef unsigned short u16;
typedef __bf16 bf16x8 __attribute__((ext_vector_type(8)));
typedef unsigned short u16x8 __attribute__((ext_vector_type(8)));
typedef float f32x16 __attribute__((ext_vector_type(16)));

#define B_ROWS 65536
#define K_NODES 4096
#define DIM 64
#define MERGE_TAU 0.0065f

#define SN 128            // nodes per stage (32 KiB)
#define HSTAGES 16        // stages per half

#define OFF_LIST 64
#define OFF_N2F  262208
#define OFF_N2D  278592
#define OFF_BFRAG 311360

#define GLOBAL_AS __attribute__((address_space(1)))
#define LDS_AS    __attribute__((address_space(3)))

__device__ __forceinline__ u16 bf16_rne(float f, float& back) {
    uint32_t u = __float_as_uint(f);
    uint32_t r = u + 0x7FFFu + ((u >> 16) & 1u);
    u16 h = (u16)(r >> 16);
    back = __uint_as_float(((uint32_t)h) << 16);
    return h;
}

__device__ __forceinline__ float pack_tile6(float v, uint32_t t) {
    return __uint_as_float((__float_as_uint(v) & 0xFFFFFFC0u) | t);   // 6-bit id
}

// ---------------- prep (merged): bfrag(-nodes) + hn2 + n2d + ref_cnt ---------
__global__ __launch_bounds__(256) void prep(const float* __restrict__ nodes,
                                            u16* __restrict__ bfrag,
                                            float* __restrict__ hn2f,
                                            double* __restrict__ n2d,
                                            int* __restrict__ ref_cnt) {
    if (blockIdx.x < 128) {
        int idx = blockIdx.x * 256 + threadIdx.x;   // (t 0..127, l 0..63, c 0..3)
        int t = idx >> 8;
        int rem = idx & 255;
        int l = rem >> 2, c = rem & 3;
        const float* row = nodes + (size_t)(t * 32 + (l & 31)) * DIM + ((l >> 5) * 8);
        float4 f0 = *(const float4*)(row + c * 16);
        float4 f1 = *(const float4*)(row + c * 16 + 4);
        float fs[8] = {-f0.x, -f0.y, -f0.z, -f0.w, -f1.x, -f1.y, -f1.z, -f1.w};
        u16x8 hv, lv;
        #pragma unroll
        for (int j = 0; j < 8; ++j) {
            float hf, dummy;
            u16 hb = bf16_rne(fs[j], hf);
            u16 lb = bf16_rne(fs[j] - hf, dummy);
            hv[j] = hb; lv[j] = lb;
        }
        int base = ((t * 4 + c) * 2) * 512 + l * 8;  // u16 index
        *(u16x8*)(bfrag + base)       = hv;
        *(u16x8*)(bfrag + base + 512) = lv;
    } else {
        if (blockIdx.x == 128 && threadIdx.x == 0) *ref_cnt = 0;
        int k = (blockIdx.x - 128) * 256 + threadIdx.x;
        if (k < K_NODES) {
            const float* r = nodes + (size_t)k * DIM;
            double s = 0.0;
            #pragma unroll
            for (int d = 0; d < DIM; ++d) { double v = (double)r[d]; s += v * v; }
            n2d[k] = s;
            hn2f[k] = 0.5f * (float)s;
        }
    }
}

// -------- phase 1: 64 rows/wave, half the nodes/block, packed-b1 top-2 -------
__global__ __launch_bounds__(256, 2) void phase1(const float* __restrict__ x,
                                                 const u16* __restrict__ bfrag_g,
                                                 const float* __restrict__ hn2f,
                                                 float* __restrict__ out) {
    __shared__ __align__(16) u16 sb[2][16384];   // 2 x 32 KiB double buffer
    const int tid  = threadIdx.x;
    const int lane = tid & 63;
    const int w    = tid >> 6;              // wave 0..3
    const int col  = lane & 31;
    const int lh   = lane >> 5;
    const int rb   = blockIdx.x >> 1;       // row block 0..255
    const int h    = blockIdx.x & 1;        // node half
    const int rbase = rb * 256 + w * 64;    // wave owns rows [rbase, rbase+64)

    // A fragments for 2 row-tiles, split hi/lo. d = lh*8 + c*16 + j
    bf16x8 ah[2][4], al[2][4];
    #pragma unroll
    for (int t = 0; t < 2; ++t) {
        const float* xp = x + (size_t)(rbase + t * 32 + col) * DIM + lh * 8;
        #pragma unroll
        for (int c = 0; c < 4; ++c) {
            float4 f0 = *(const float4*)(xp + c * 16);
            float4 f1 = *(const float4*)(xp + c * 16 + 4);
            float fs[8] = {f0.x, f0.y, f0.z, f0.w, f1.x, f1.y, f1.z, f1.w};
            u16x8 hv, lv;
            #pragma unroll
            for (int j = 0; j < 8; ++j) {
                float hf, dummy;
                u16 hb = bf16_rne(fs[j], hf);
                u16 lb = bf16_rne(fs[j] - hf, dummy);
                hv[j] = hb; lv[j] = lb;
            }
            union { u16x8 u; bf16x8 b; } cvh, cvl;
            cvh.u = hv; cvl.u = lv;
            ah[t][c] = cvh.b; al[t][c] = cvl.b;
        }
    }

    float b1[2][16], v2[2][16];
    #pragma unroll
    for (int t = 0; t < 2; ++t)
        #pragma unroll
        for (int q = 0; q < 16; ++q) { b1[t][q] = 3.4e38f; v2[t][q] = 3.4e38f; }

    const char* gbase = (const char*)bfrag_g;
    const float* hp = hn2f + col;
    const int s0g = h * HSTAGES;

    // prologue: first stage of this half (32 KiB: 256 thr x 16B x 8 rounds)
    {
        const char* gp = gbase + (size_t)s0g * 32768 + tid * 16;
        const char* lp = (const char*)&sb[0][0] + tid * 16;
        #pragma unroll
        for (int i = 0; i < 8; ++i)
            __builtin_amdgcn_global_load_lds(
                (const GLOBAL_AS uint32_t*)(gp + i * 4096),
                (LDS_AS uint32_t*)(lp + i * 4096), 16, 0, 0);
    }
    __syncthreads();

    int cur = 0;
    for (int sl = 0; sl < HSTAGES; ++sl) {
        const int s = s0g + sl;
        if (sl + 1 < HSTAGES) {
            const char* gp = gbase + (size_t)(s + 1) * 32768 + tid * 16;
            const char* lp = (const char*)&sb[cur ^ 1][0] + tid * 16;
            #pragma unroll
            for (int i = 0; i < 8; ++i)
                __builtin_amdgcn_global_load_lds(
                    (const GLOBAL_AS uint32_t*)(gp + i * 4096),
                    (LDS_AS uint32_t*)(lp + i * 4096), 16, 0, 0);
        }

        float hn2v[4];
        #pragma unroll
        for (int nt = 0; nt < 4; ++nt) hn2v[nt] = hp[s * SN + nt * 32];

        const u16* bb = &sb[cur][0];
        #pragma unroll
        for (int nt = 0; nt < 4; ++nt) {
            f32x16 a0, a1;
            #pragma unroll
            for (int q = 0; q < 16; ++q) { a0[q] = hn2v[nt]; a1[q] = hn2v[nt]; }
            #pragma unroll
            for (int c = 0; c < 4; ++c) {
                const bf16x8 bh = *(const bf16x8*)(bb + ((nt * 4 + c) * 2 + 0) * 512 + lane * 8);
                const bf16x8 bl = *(const bf16x8*)(bb + ((nt * 4 + c) * 2 + 1) * 512 + lane * 8);
                a0 = __builtin_amdgcn_mfma_f32_32x32x16_bf16(ah[0][c], bh, a0, 0, 0, 0);
                a1 = __builtin_amdgcn_mfma_f32_32x32x16_bf16(ah[1][c], bh, a1, 0, 0, 0);
                a0 = __builtin_amdgcn_mfma_f32_32x32x16_bf16(al[0][c], bh, a0, 0, 0, 0);
                a1 = __builtin_amdgcn_mfma_f32_32x32x16_bf16(al[1][c], bh, a1, 0, 0, 0);
                a0 = __builtin_amdgcn_mfma_f32_32x32x16_bf16(ah[0][c], bl, a0, 0, 0, 0);
                a1 = __builtin_amdgcn_mfma_f32_32x32x16_bf16(ah[1][c], bl, a1, 0, 0, 0);
            }
            const uint32_t tb = (uint32_t)(sl * 4 + nt);   // stage-LOCAL tile id, 6 bits
            #pragma unroll
            for (int q = 0; q < 16; ++q) {
                float p0 = pack_tile6(a0[q], tb);
                v2[0][q] = __builtin_amdgcn_fmed3f(v2[0][q], p0, b1[0][q]);  // == min(v2,max(p,b1)), b1<=v2
                b1[0][q] = fminf(b1[0][q], p0);
                float p1 = pack_tile6(a1[q], tb);
                v2[1][q] = __builtin_amdgcn_fmed3f(v2[1][q], p1, b1[1][q]);
                b1[1][q] = fminf(b1[1][q], p1);
            }
        }

        __syncthreads();
        cur ^= 1;
    }

    // recover GLOBAL node index from b1's 6-bit tile id + col (+ half offset)
    int gi[2][16];
    #pragma unroll
    for (int t = 0; t < 2; ++t)
        #pragma unroll
        for (int q = 0; q < 16; ++q)
            gi[t][q] = h * 2048 + (int)(__float_as_uint(b1[t][q]) & 63u) * 32 + col;

    // reduce (b1, gi, v2) across the 32 cols (within each lane-half)
    #pragma unroll
    for (int off = 1; off < 32; off <<= 1) {
        #pragma unroll
        for (int t = 0; t < 2; ++t)
            #pragma unroll
            for (int q = 0; q < 16; ++q) {
                float ov  = __shfl_xor(b1[t][q], off, 64);
                float ov2 = __shfl_xor(v2[t][q], off, 64);
                int   og  = __shfl_xor(gi[t][q], off, 64);
                float hi2 = fmaxf(b1[t][q], ov);
                v2[t][q] = fminf(fminf(v2[t][q], ov2), hi2);
                bool take = (ov < b1[t][q]) || (ov == b1[t][q] && og < gi[t][q]);
                b1[t][q] = take ? ov : b1[t][q];
                gi[t][q] = take ? og : gi[t][q];
            }
    }

    if (col == 0) {                  // lanes 0 and 32 of each wave
        #pragma unroll
        for (int t = 0; t < 2; ++t)
            #pragma unroll
            for (int q = 0; q < 16; ++q) {
                int rloc = (q & 3) + 8 * (q >> 2) + 4 * lh;   // C/D layout (verified r1-r22)
                int grow = rb * 256 + w * 64 + t * 32 + rloc;
                // candidate in out's repr row (overwritten by merge's gather):
                // (b1, v2) at h*2, exact global index as float at 4+h
                *(float2*)(out + (size_t)grow * DIM + h * 2) = make_float2(b1[t][q], v2[t][q]);
                out[(size_t)grow * DIM + 4 + h] = (float)gi[t][q];
            }
    }
}

// -------- merge: combine halves, write index, gather, flag refines -----------
__global__ __launch_bounds__(256) void merge_k(const float* __restrict__ nodes,
                                               float* __restrict__ out,
                                               int* __restrict__ ref_cnt,
                                               int* __restrict__ ref_list) {
    __shared__ int s_win[256];
    const int tid = threadIdx.x;
    const int row = blockIdx.x * 256 + tid;
    float4 cv = *(const float4*)(out + (size_t)row * DIM);       // (b1h0, v2h0, b1h1, v2h1)
    float2 ci = *(const float2*)(out + (size_t)row * DIM + 4);   // (idx h0, idx h1)
    bool h1w = cv.z < cv.x;          // h0 wins ties (lower index); near-ties flagged below
    float wb  = h1w ? cv.z : cv.x;
    float lb  = h1w ? cv.x : cv.z;
    float v2m = fminf(fminf(cv.y, cv.w), lb);
    int gi = (int)(h1w ? ci.y : ci.x);
    out[(size_t)B_ROWS * DIM + row] = (float)gi;
    if (v2m - wb <= MERGE_TAU) {
        int slot = atomicAdd(ref_cnt, 1);
        ref_list[slot] = row;
    }
    s_win[tid] = gi;
    __syncthreads();                 // all candidate reads done before gather overwrites
    const int base_row = blockIdx.x * 256;
    for (int i = tid; i < 256 * 16; i += 256) {
        int rr = i >> 4, cc = i & 15;
        int wn = s_win[rr];
        float4 v = *(const float4*)(nodes + (size_t)wn * DIM + cc * 4);
        *(float4*)(out + (size_t)(base_row + rr) * DIM + cc * 4) = v;
    }
}

// ------ phase 2: exact f64 re-solve, 2 rows per nodes pass -------------------
__global__ __launch_bounds__(256) void phase2(const float* __restrict__ x,
                                              const float* __restrict__ nodes,
                                              const double* __restrict__ n2d,
                                              const int* __restrict__ ref_cnt,
                                              const int* __restrict__ ref_list,
                                              float* __restrict__ out) {
    __shared__ double xsA[DIM], xsB[DIM];
    __shared__ double sval[256];
    __shared__ int    sidx[256];
    __shared__ int    rows_s[2];
    const int tid = threadIdx.x;
    const int cnt = *ref_cnt;
    for (int b0 = blockIdx.x * 2; b0 < cnt; b0 += gridDim.x * 2) {
        const int nr = min(2, cnt - b0);
        __syncthreads();                 // guard xs/rows reuse across batches
        if (tid < 2) rows_s[tid] = ref_list[b0 + min(tid, nr - 1)];
        __syncthreads();
        if (tid < DIM) {
            xsA[tid] = (double)x[(size_t)rows_s[0] * DIM + tid];
            xsB[tid] = (double)x[(size_t)rows_s[1] * DIM + tid];
        }
        __syncthreads();

        double bestA = 1e300, bestB = 1e300;
        int    biA = K_NODES, biB = K_NODES;
        for (int k = tid; k < K_NODES; k += 256) {
            const float4* np4 = (const float4*)(nodes + (size_t)k * DIM);
            double a0 = 0.0, a1 = 0.0, b0d = 0.0, b1d = 0.0;
            #pragma unroll
            for (int t = 0; t < 16; t += 2) {
                float4 w0 = np4[t], w1 = np4[t + 1];
                a0 += xsA[t*4+0]*(double)w0.x + xsA[t*4+1]*(double)w0.y
                    + xsA[t*4+2]*(double)w0.z + xsA[t*4+3]*(double)w0.w;
                b0d += xsB[t*4+0]*(double)w0.x + xsB[t*4+1]*(double)w0.y
                     + xsB[t*4+2]*(double)w0.z + xsB[t*4+3]*(double)w0.w;
                a1 += xsA[t*4+4]*(double)w1.x + xsA[t*4+5]*(double)w1.y
                    + xsA[t*4+6]*(double)w1.z + xsA[t*4+7]*(double)w1.w;
                b1d += xsB[t*4+4]*(double)w1.x + xsB[t*4+5]*(double)w1.y
                     + xsB[t*4+6]*(double)w1.z + xsB[t*4+7]*(double)w1.w;
            }
            const double nn = n2d[k];
            double sA = nn - 2.0 * (a0 + a1);
            double sB = nn - 2.0 * (b0d + b1d);
            if (sA < bestA) { bestA = sA; biA = k; }
            if (sB < bestB) { bestB = sB; biB = k; }
        }

        #pragma unroll 1
        for (int r = 0; r < nr; ++r) {
            sval[tid] = (r == 0) ? bestA : bestB;
            sidx[tid] = (r == 0) ? biA : biB;
            __syncthreads();
            for (int stride = 128; stride > 0; stride >>= 1) {
                if (tid < (unsigned)stride) {
                    double ov = sval[tid + stride];
                    int    oi = sidx[tid + stride];
                    if (ov < sval[tid] || (ov == sval[tid] && oi < sidx[tid])) {
                        sval[tid] = ov; sidx[tid] = oi;
                    }
                }
                __syncthreads();
            }
            const int wn = sidx[0];
            const int row = rows_s[r];
            if (tid == 0) out[(size_t)B_ROWS * DIM + row] = (float)wn;
            if (tid < 16) {
                float4 v = *(const float4*)(nodes + (size_t)wn * DIM + tid * 4);
                *(float4*)(out + (size_t)row * DIM + tid * 4) = v;
            }
            __syncthreads();
        }
    }
}

extern "C" void kernel_launch(void* const* d_in, const int* in_sizes, int n_in,
                              void* d_out, int out_size, void* d_ws, size_t ws_size,
                              hipStream_t stream) {
    const float* x     = (const float*)d_in[0];
    const float* nodes = (const float*)d_in[1];
    float* out = (float*)d_out;
    char*  ws  = (char*)d_ws;

    int*    ref_cnt  = (int*)ws;
    int*    ref_list = (int*)(ws + OFF_LIST);
    float*  hn2f     = (float*)(ws + OFF_N2F);
    double* n2d      = (double*)(ws + OFF_N2D);
    u16*    bfrag    = (u16*)(ws + OFF_BFRAG);

    prep<<<144, 256, 0, stream>>>(nodes, bfrag, hn2f, n2d, ref_cnt);
    phase1<<<512, 256, 0, stream>>>(x, bfrag, hn2f, out);
    merge_k<<<B_ROWS / 256, 256, 0, stream>>>(nodes, out, ref_cnt, ref_list);
    phase2<<<1024, 256, 0, stream>>>(x, nodes, n2d, ref_cnt, ref_list, out);
}